// Round 1
// baseline (2722.319 us; speedup 1.0000x reference)
//
#include <hip/hip_runtime.h>

typedef _Float16 h2_t __attribute__((ext_vector_type(2)));
typedef short bf16x8 __attribute__((ext_vector_type(8)));
typedef float f32x4 __attribute__((ext_vector_type(4)));

// ---------------------------------------------------------------- utilities
__device__ inline unsigned short bfc(float f) {
    unsigned int u = __builtin_bit_cast(unsigned int, f);
    unsigned int r = (u + 0x7FFFu + ((u >> 16) & 1u)) >> 16;
    return (unsigned short)r;
}

__device__ inline float fdot2f(h2_t a, h2_t b, float c) {
#if __has_builtin(__builtin_amdgcn_fdot2)
    return __builtin_amdgcn_fdot2(a, b, c, false);
#else
    return c + (float)a[0] * (float)b[0] + (float)a[1] * (float)b[1];
#endif
}

// quad (4-lane) butterfly sum via DPP quad_perm — stays on the VALU pipe.
__device__ inline float qsum4(float x) {
    int xi = __builtin_bit_cast(int, x);
    int y = __builtin_amdgcn_mov_dpp(xi, 0xB1, 0xF, 0xF, true); // [1,0,3,2]
    float s = x + __builtin_bit_cast(float, y);
    int si = __builtin_bit_cast(int, s);
    int z = __builtin_amdgcn_mov_dpp(si, 0x4E, 0xF, 0xF, true); // [2,3,0,1]
    return s + __builtin_bit_cast(float, z);
}

#define AS1P(p) ((const __attribute__((address_space(1))) void*)(uintptr_t)(p))
#define AS3P(p) ((__attribute__((address_space(3))) void*)(uintptr_t)(p))

// ---------------------------------------------------------------- converts
__global__ void cvt_bf16(const float* __restrict__ in, unsigned short* __restrict__ out, int n4) {
    int i = blockIdx.x * blockDim.x + threadIdx.x;
    int stride = gridDim.x * blockDim.x;
    for (; i < n4; i += stride) {
        float4 v = ((const float4*)in)[i];
        ushort4 o = make_ushort4(bfc(v.x), bfc(v.y), bfc(v.z), bfc(v.w));
        ((ushort4*)out)[i] = o;
    }
}

// pack W_hh fp32 [768,256] -> fp16, per-thread register layout for gru_scan.
// thread t (0..767): u=t>>2 -> rows 4u..4u+3 ; v=t&3 -> K in [64v,64v+64)
// dword i2 = r*32+k2 holds pair (W[4u+r][64v+2k2], W[4u+r][64v+2k2+1])
// stored as uint4 blocks: out_u4[i*768 + t] = dwords i2=4i..4i+3
__global__ void pack_whh(const float* __restrict__ W, unsigned short* __restrict__ out) {
    int gid = blockIdx.x * 256 + threadIdx.x;   // [0, 196608)
    int e = gid & 7;                            // ushort within 16B block
    int rr = gid >> 3;
    int t = rr % 768;
    int i = rr / 768;                           // uint4 slot [0,32)
    int i2 = i * 4 + (e >> 1);                  // dword index [0,128)
    int r = i2 >> 5;
    int k2 = i2 & 31;
    int row = 4 * (t >> 2) + r;
    int col = 64 * (t & 3) + 2 * k2 + (e & 1);
    _Float16 hv = (_Float16)W[row * 256 + col];
    out[gid] = __builtin_bit_cast(unsigned short, hv);
}

// cb[g] = b_ih[g] + (g<512 ? b_hh[g] : 0)  — b_hn stays separate (inside r*(...))
__global__ void bias_comb(const float* __restrict__ b_ih, const float* __restrict__ b_hh,
                          float* __restrict__ cb) {
    int g = blockIdx.x * 256 + threadIdx.x;
    if (g < 768) cb[g] = b_ih[g] + (g < 512 ? b_hh[g] : 0.0f);
}

// ---------------------------------------------------------------- projection GEMM
// C[131072][768] = A(x bf16 [131072][256]) * B(W_ih bf16 [768][256])^T + cb
// m97 structure: 128x128 tile, BK=32, 256 threads, global_load_lds(16B)
__launch_bounds__(256)
__global__ void proj_gemm(const unsigned short* __restrict__ A,
                          const unsigned short* __restrict__ Bw,
                          const float* __restrict__ cb,
                          float* __restrict__ C) {
    __shared__ __align__(16) unsigned short As[128 * 32];
    __shared__ __align__(16) unsigned short Bs[128 * 32];
    const int tid = threadIdx.x;
    const int lane = tid & 63;
    const int wv = tid >> 6;               // 0..3
    const int mt = blockIdx.x / 6;
    const int nt = blockIdx.x % 6;
    const unsigned short* Ab = A + (size_t)mt * 128 * 256;
    const unsigned short* Bb = Bw + (size_t)nt * 128 * 256;

    f32x4 acc[4][4] = {};

    for (int kt = 0; kt < 8; ++kt) {
        __syncthreads();
        // stage tiles: each wave issues 2x 1KB per matrix (rows wv*32 .. wv*32+31)
#pragma unroll
        for (int q = 0; q < 2; ++q) {
            int rowb = wv * 32 + q * 16;                  // wave-uniform
            int row = rowb + (lane >> 2);
            int cc = lane & 3;
            const unsigned short* sA = Ab + (size_t)row * 256 + kt * 32 + cc * 8;
            const unsigned short* sB = Bb + (size_t)row * 256 + kt * 32 + cc * 8;
            __builtin_amdgcn_global_load_lds(AS1P(sA), AS3P((char*)As + rowb * 64), 16, 0, 0);
            __builtin_amdgcn_global_load_lds(AS1P(sB), AS3P((char*)Bs + rowb * 64), 16, 0, 0);
        }
        __syncthreads();

        bf16x8 af[4], bfq[4];
#pragma unroll
        for (int m = 0; m < 4; m++) {
            int r = (wv >> 1) * 64 + m * 16 + (lane & 15);
            af[m] = *(const bf16x8*)&As[r * 32 + (lane >> 4) * 8];
        }
#pragma unroll
        for (int n = 0; n < 4; n++) {
            int r = (wv & 1) * 64 + n * 16 + (lane & 15);
            bfq[n] = *(const bf16x8*)&Bs[r * 32 + (lane >> 4) * 8];
        }
#pragma unroll
        for (int m = 0; m < 4; m++)
#pragma unroll
            for (int n = 0; n < 4; n++)
                acc[m][n] = __builtin_amdgcn_mfma_f32_16x16x32_bf16(af[m], bfq[n], acc[m][n], 0, 0, 0);
    }

    // epilogue: C/D layout col=lane&15, row=(lane>>4)*4+e  [m89]
    const int r_base = mt * 128 + (wv >> 1) * 64 + (lane >> 4) * 4;
    const int c_base = nt * 128 + (wv & 1) * 64 + (lane & 15);
#pragma unroll
    for (int n = 0; n < 4; n++) {
        float bv = cb[c_base + n * 16];
#pragma unroll
        for (int m = 0; m < 4; m++) {
            int r0 = r_base + m * 16;
#pragma unroll
            for (int e = 0; e < 4; e++) {
                C[(size_t)(r0 + e) * 768 + c_base + n * 16] = acc[m][n][e] + bv;
            }
        }
    }
}

// ---------------------------------------------------------------- recurrent scan
// 64 blocks (one batch each) x 768 threads (12 waves, 3/SIMD).
// thread t: u=t>>2 owns gate-rows 4u..4u+3 ; v=t&3 owns K-quarter [64v,64v+64).
// W_hh fp16 pairs register-resident (128 dwords). h in LDS as fp16x2, padded per quarter.
__launch_bounds__(768, 1)
__global__ void gru_scan(const float* __restrict__ xg,          // [64][2048][768]
                         const unsigned short* __restrict__ wpk, // packed uint4[32][768]
                         const float* __restrict__ b_hh,         // [768]
                         const float* __restrict__ h0,           // [64][256]
                         float* __restrict__ out_hs,             // [64][2048][256]
                         float* __restrict__ out_hT) {           // [64][256]
    const int b = blockIdx.x;
    const int tid = threadIdx.x;
    const int v = tid & 3;
    const int u = tid >> 2;

    // h as fp16x2: 4 quarters x (32 pairs + 4 pad pairs) -> 144B row stride (bank offset)
    __shared__ __align__(16) unsigned short hl2[4][72];
    __shared__ __align__(16) float buf[768];

    // ---- preload weights into registers (128 dwords = 128 fp16-pairs)
    unsigned int wd[128];
    {
        const uint4* wp4 = (const uint4*)wpk;
#pragma unroll
        for (int i = 0; i < 32; i++) {
            uint4 q = wp4[(size_t)i * 768 + tid];
            wd[4 * i + 0] = q.x; wd[4 * i + 1] = q.y;
            wd[4 * i + 2] = q.z; wd[4 * i + 3] = q.w;
        }
    }

    float bhn = (tid < 256) ? b_hh[512 + tid] : 0.0f;
    float h_reg = (tid < 256) ? h0[b * 256 + tid] : 0.0f;

    if (tid < 128) {
        float a0 = h0[b * 256 + 2 * tid];
        float a1 = h0[b * 256 + 2 * tid + 1];
        h2_t p; p[0] = (_Float16)a0; p[1] = (_Float16)a1;
        *(unsigned int*)&hl2[tid >> 5][(tid & 31) * 2] = __builtin_bit_cast(unsigned int, p);
    }
    __syncthreads();

    const float* xgb = xg + (size_t)b * 2048 * 768;
    float* outb = out_hs + (size_t)b * 2048 * 256;

    for (int t = 0; t < 2048; ++t) {
        // prefetch xg for phase B (hidden under phase A compute)
        float xr = 0.f, xz = 0.f, xn = 0.f;
        if (tid < 256) {
            const float* xgt = xgb + (size_t)t * 768;
            xr = xgt[tid]; xz = xgt[256 + tid]; xn = xgt[512 + tid];
        }

        // ---- phase A: partial hg over this thread's K-quarter, 4 rows
        float a0 = 0.f, a1 = 0.f, a2 = 0.f, a3 = 0.f;
        const uint4* hlv4 = (const uint4*)(&hl2[v][0]);
#pragma unroll
        for (int c = 0; c < 8; c++) {
            uint4 hq = hlv4[c];
#pragma unroll
            for (int jj = 0; jj < 4; jj++) {
                unsigned int hdw = (jj == 0) ? hq.x : (jj == 1) ? hq.y : (jj == 2) ? hq.z : hq.w;
                h2_t hp = __builtin_bit_cast(h2_t, hdw);
                int k2 = c * 4 + jj;
                a0 = fdot2f(__builtin_bit_cast(h2_t, wd[k2]), hp, a0);
                a1 = fdot2f(__builtin_bit_cast(h2_t, wd[32 + k2]), hp, a1);
                a2 = fdot2f(__builtin_bit_cast(h2_t, wd[64 + k2]), hp, a2);
                a3 = fdot2f(__builtin_bit_cast(h2_t, wd[96 + k2]), hp, a3);
            }
        }
        // reduce across the 4 K-quarters (lanes differing in bits 0..1)
        a0 = qsum4(a0); a1 = qsum4(a1); a2 = qsum4(a2); a3 = qsum4(a3);
        if (v == 0) {
            float4 st = make_float4(a0, a1, a2, a3);
            *(float4*)&buf[4 * u] = st;
        }
        __syncthreads();

        // ---- phase B: gates + state update (threads 0..255 = hidden units)
        if (tid < 256) {
            float hr = buf[tid];
            float hz = buf[256 + tid];
            float hn = buf[512 + tid] + bhn;
            float r = 1.0f / (1.0f + __expf(-(xr + hr)));
            float z = 1.0f / (1.0f + __expf(-(xz + hz)));
            float pre = xn + r * hn;
            float n = 1.0f - 2.0f / (__expf(2.0f * pre) + 1.0f); // tanh
            float hnew = (1.0f - z) * n + z * h_reg;
            h_reg = hnew;
            outb[(size_t)t * 256 + tid] = hnew;
            float nb = __shfl_xor(hnew, 1);
            if (!(tid & 1)) {
                int k = tid >> 1;
                h2_t p; p[0] = (_Float16)hnew; p[1] = (_Float16)nb;
                *(unsigned int*)&hl2[k >> 5][(k & 31) * 2] = __builtin_bit_cast(unsigned int, p);
            }
        }
        __syncthreads();
    }

    if (tid < 256) out_hT[b * 256 + tid] = h_reg;
}

// ---------------------------------------------------------------- launch
extern "C" void kernel_launch(void* const* d_in, const int* in_sizes, int n_in,
                              void* d_out, int out_size, void* d_ws, size_t ws_size,
                              hipStream_t stream) {
    const float* x    = (const float*)d_in[0];
    const float* h0   = (const float*)d_in[1];
    const float* W_ih = (const float*)d_in[2];
    const float* W_hh = (const float*)d_in[3];
    const float* b_ih = (const float*)d_in[4];
    const float* b_hh = (const float*)d_in[5];
    float* out = (float*)d_out;

    char* ws = (char*)d_ws;
    float*          xg  = (float*)(ws);                      // 402,653,184 B
    unsigned short* xb  = (unsigned short*)(ws + 402653184); //  67,108,864 B
    unsigned short* wib = (unsigned short*)(ws + 469762048); //     393,216 B
    unsigned short* whp = (unsigned short*)(ws + 470155264); //     393,216 B
    float*          cb  = (float*)(ws + 470548480);          //       3,072 B

    cvt_bf16<<<4096, 256, 0, stream>>>(x, xb, 64 * 2048 * 256 / 4);
    cvt_bf16<<<192, 256, 0, stream>>>(W_ih, wib, 768 * 256 / 4);
    pack_whh<<<768, 256, 0, stream>>>(W_hh, whp);
    bias_comb<<<3, 256, 0, stream>>>(b_ih, b_hh, cb);
    proj_gemm<<<6144, 256, 0, stream>>>(xb, wib, cb, xg);
    gru_scan<<<64, 768, 0, stream>>>(xg, whp, b_hh, h0, out,
                                     out + (size_t)64 * 2048 * 256);
}

// Round 3
// 2644.354 us; speedup vs baseline: 1.0295x; 1.0295x over previous
//
#include <hip/hip_runtime.h>

typedef _Float16 h2_t __attribute__((ext_vector_type(2)));
typedef short bf16x8 __attribute__((ext_vector_type(8)));
typedef float f32x4 __attribute__((ext_vector_type(4)));

// ---------------------------------------------------------------- utilities
__device__ inline unsigned short bfc(float f) {
    unsigned int u = __builtin_bit_cast(unsigned int, f);
    unsigned int r = (u + 0x7FFFu + ((u >> 16) & 1u)) >> 16;
    return (unsigned short)r;
}

__device__ inline float fdot2f(h2_t a, h2_t b, float c) {
#if __has_builtin(__builtin_amdgcn_fdot2)
    return __builtin_amdgcn_fdot2(a, b, c, false);
#else
    return c + (float)a[0] * (float)b[0] + (float)a[1] * (float)b[1];
#endif
}

// quad (4-lane) butterfly sum via DPP quad_perm — stays on the VALU pipe.
__device__ inline float qsum4(float x) {
    int xi = __builtin_bit_cast(int, x);
    int y = __builtin_amdgcn_mov_dpp(xi, 0xB1, 0xF, 0xF, true); // [1,0,3,2]
    float s = x + __builtin_bit_cast(float, y);
    int si = __builtin_bit_cast(int, s);
    int z = __builtin_amdgcn_mov_dpp(si, 0x4E, 0xF, 0xF, true); // [2,3,0,1]
    return s + __builtin_bit_cast(float, z);
}

#define AS1P(p) ((const __attribute__((address_space(1))) void*)(uintptr_t)(p))
#define AS3P(p) ((__attribute__((address_space(3))) void*)(uintptr_t)(p))

// ---------------------------------------------------------------- converts
__global__ void cvt_bf16(const float* __restrict__ in, unsigned short* __restrict__ out, int n4) {
    int i = blockIdx.x * blockDim.x + threadIdx.x;
    int stride = gridDim.x * blockDim.x;
    for (; i < n4; i += stride) {
        float4 v = ((const float4*)in)[i];
        ushort4 o = make_ushort4(bfc(v.x), bfc(v.y), bfc(v.z), bfc(v.w));
        ((ushort4*)out)[i] = o;
    }
}

// pack W_hh fp32 [768,256] -> fp16, per-thread register layout for gru_scan.
// thread t (0..767): u=t>>2 -> rows 4u..4u+3 ; v=t&3 -> K in [64v,64v+64)
// dword i2 = r*32+k2 holds pair (W[4u+r][64v+2k2], W[4u+r][64v+2k2+1])
// stored as uint4 blocks: out_u4[i*768 + t] = dwords i2=4i..4i+3
__global__ void pack_whh(const float* __restrict__ W, unsigned short* __restrict__ out) {
    int gid = blockIdx.x * 256 + threadIdx.x;   // [0, 196608)
    int e = gid & 7;                            // ushort within 16B block
    int rr = gid >> 3;
    int t = rr % 768;
    int i = rr / 768;                           // uint4 slot [0,32)
    int i2 = i * 4 + (e >> 1);                  // dword index [0,128)
    int r = i2 >> 5;
    int k2 = i2 & 31;
    int row = 4 * (t >> 2) + r;
    int col = 64 * (t & 3) + 2 * k2 + (e & 1);
    _Float16 hv = (_Float16)W[row * 256 + col];
    out[gid] = __builtin_bit_cast(unsigned short, hv);
}

// cb[g] = b_ih[g] + (g<512 ? b_hh[g] : 0)  — b_hn stays separate (inside r*(...))
__global__ void bias_comb(const float* __restrict__ b_ih, const float* __restrict__ b_hh,
                          float* __restrict__ cb) {
    int g = blockIdx.x * 256 + threadIdx.x;
    if (g < 768) cb[g] = b_ih[g] + (g < 512 ? b_hh[g] : 0.0f);
}

// ---------------------------------------------------------------- projection GEMM
// C[131072][768] = A(x bf16 [131072][256]) * B(W_ih bf16 [768][256])^T + cb
// m97 structure: 128x128 tile, BK=32, 256 threads, global_load_lds(16B)
__launch_bounds__(256)
__global__ void proj_gemm(const unsigned short* __restrict__ A,
                          const unsigned short* __restrict__ Bw,
                          const float* __restrict__ cb,
                          float* __restrict__ C) {
    __shared__ __align__(16) unsigned short As[128 * 32];
    __shared__ __align__(16) unsigned short Bs[128 * 32];
    const int tid = threadIdx.x;
    const int lane = tid & 63;
    const int wv = tid >> 6;               // 0..3
    const int mt = blockIdx.x / 6;
    const int nt = blockIdx.x % 6;
    const unsigned short* Ab = A + (size_t)mt * 128 * 256;
    const unsigned short* Bb = Bw + (size_t)nt * 128 * 256;

    f32x4 acc[4][4] = {};

    for (int kt = 0; kt < 8; ++kt) {
        __syncthreads();
        // stage tiles: each wave issues 2x 1KB per matrix (rows wv*32 .. wv*32+31)
#pragma unroll
        for (int q = 0; q < 2; ++q) {
            int rowb = wv * 32 + q * 16;                  // wave-uniform
            int row = rowb + (lane >> 2);
            int cc = lane & 3;
            const unsigned short* sA = Ab + (size_t)row * 256 + kt * 32 + cc * 8;
            const unsigned short* sB = Bb + (size_t)row * 256 + kt * 32 + cc * 8;
            __builtin_amdgcn_global_load_lds(AS1P(sA), AS3P((char*)As + rowb * 64), 16, 0, 0);
            __builtin_amdgcn_global_load_lds(AS1P(sB), AS3P((char*)Bs + rowb * 64), 16, 0, 0);
        }
        __syncthreads();

        bf16x8 af[4], bfq[4];
#pragma unroll
        for (int m = 0; m < 4; m++) {
            int r = (wv >> 1) * 64 + m * 16 + (lane & 15);
            af[m] = *(const bf16x8*)&As[r * 32 + (lane >> 4) * 8];
        }
#pragma unroll
        for (int n = 0; n < 4; n++) {
            int r = (wv & 1) * 64 + n * 16 + (lane & 15);
            bfq[n] = *(const bf16x8*)&Bs[r * 32 + (lane >> 4) * 8];
        }
#pragma unroll
        for (int m = 0; m < 4; m++)
#pragma unroll
            for (int n = 0; n < 4; n++)
                acc[m][n] = __builtin_amdgcn_mfma_f32_16x16x32_bf16(af[m], bfq[n], acc[m][n], 0, 0, 0);
    }

    // epilogue: C/D layout col=lane&15, row=(lane>>4)*4+e  [m89]
    const int r_base = mt * 128 + (wv >> 1) * 64 + (lane >> 4) * 4;
    const int c_base = nt * 128 + (wv & 1) * 64 + (lane & 15);
#pragma unroll
    for (int n = 0; n < 4; n++) {
        float bv = cb[c_base + n * 16];
#pragma unroll
        for (int m = 0; m < 4; m++) {
            int r0 = r_base + m * 16;
#pragma unroll
            for (int e = 0; e < 4; e++) {
                C[(size_t)(r0 + e) * 768 + c_base + n * 16] = acc[m][n][e] + bv;
            }
        }
    }
}

// ---------------------------------------------------------------- recurrent scan
// 64 blocks (one batch each) x 768 threads (12 waves, 3/SIMD -> VGPR cap 170).
// thread t: u=t>>2 owns gate-rows 4u..4u+3 ; v=t&3 owns K-quarter [64v,64v+64).
// W_hh fp16 pairs register-resident: 128 scalar dwords, each pinned with a
// 32-bit "+v" keepalive (the asm becomes the def -> no remat-from-L2 in-loop;
// scalar ties avoid the 128-bit-tuple allocator miscompile seen in R2).
__launch_bounds__(768, 1)
__global__ void gru_scan(const float* __restrict__ xg,          // [64][2048][768]
                         const unsigned short* __restrict__ wpk, // packed uint4[32][768]
                         const float* __restrict__ b_hh,         // [768]
                         const float* __restrict__ h0,           // [64][256]
                         float* __restrict__ out_hs,             // [64][2048][256]
                         float* __restrict__ out_hT) {           // [64][256]
    const int b = blockIdx.x;
    const int tid = threadIdx.x;
    const int v = tid & 3;
    const int u = tid >> 2;

    // h as fp16x2: 4 quarters x (32 pairs + 4 pad pairs) -> 144B quarter stride
    __shared__ __align__(16) unsigned short hl2[4][72];
    __shared__ __align__(16) float buf[768];

    // ---- preload weights into pinned VGPRs (128 scalar dwords)
    unsigned int wd[128];
    {
        const uint4* wp4 = (const uint4*)wpk;
#pragma unroll
        for (int i = 0; i < 32; i++) {
            uint4 q = wp4[(size_t)i * 768 + tid];
            wd[4 * i + 0] = q.x; wd[4 * i + 1] = q.y;
            wd[4 * i + 2] = q.z; wd[4 * i + 3] = q.w;
        }
#pragma unroll
        for (int i = 0; i < 128; i++) asm volatile("" : "+v"(wd[i]));
    }

    float bhn = (tid < 256) ? b_hh[512 + tid] : 0.0f;
    float h_reg = (tid < 256) ? h0[b * 256 + tid] : 0.0f;

    if (tid < 128) {
        float a0 = h0[b * 256 + 2 * tid];
        float a1 = h0[b * 256 + 2 * tid + 1];
        h2_t p; p[0] = (_Float16)a0; p[1] = (_Float16)a1;
        *(unsigned int*)&hl2[tid >> 5][(tid & 31) * 2] = __builtin_bit_cast(unsigned int, p);
    }
    __syncthreads();

    const float* xgb = xg + (size_t)b * 2048 * 768;
    float* outb = out_hs + (size_t)b * 2048 * 256;

    for (int t = 0; t < 2048; ++t) {
        // prefetch xg for phase B (hidden under phase A compute)
        float xr = 0.f, xz = 0.f, xn = 0.f;
        if (tid < 256) {
            const float* xgt = xgb + (size_t)t * 768;
            xr = xgt[tid]; xz = xgt[256 + tid]; xn = xgt[512 + tid];
        }

        // ---- phase A: partial hg over this thread's K-quarter, 4 rows
        float a0 = 0.f, a1 = 0.f, a2 = 0.f, a3 = 0.f;
        const uint4* hlv4 = (const uint4*)(&hl2[v][0]);
#pragma unroll
        for (int c = 0; c < 8; c++) {
            uint4 hq = hlv4[c];
#pragma unroll
            for (int jj = 0; jj < 4; jj++) {
                unsigned int hdw = (jj == 0) ? hq.x : (jj == 1) ? hq.y : (jj == 2) ? hq.z : hq.w;
                h2_t hp = __builtin_bit_cast(h2_t, hdw);
                int k2 = c * 4 + jj;
                a0 = fdot2f(__builtin_bit_cast(h2_t, wd[k2]), hp, a0);
                a1 = fdot2f(__builtin_bit_cast(h2_t, wd[32 + k2]), hp, a1);
                a2 = fdot2f(__builtin_bit_cast(h2_t, wd[64 + k2]), hp, a2);
                a3 = fdot2f(__builtin_bit_cast(h2_t, wd[96 + k2]), hp, a3);
            }
        }
        // reduce across the 4 K-quarters (lanes differing in bits 0..1)
        a0 = qsum4(a0); a1 = qsum4(a1); a2 = qsum4(a2); a3 = qsum4(a3);
        if (v == 0) {
            float4 st = make_float4(a0, a1, a2, a3);
            *(float4*)&buf[4 * u] = st;
        }
        __syncthreads();

        // ---- phase B: gates + state update (threads 0..255 = hidden units)
        if (tid < 256) {
            float hr = buf[tid];
            float hz = buf[256 + tid];
            float hn = buf[512 + tid] + bhn;
            float r = 1.0f / (1.0f + __expf(-(xr + hr)));
            float z = 1.0f / (1.0f + __expf(-(xz + hz)));
            float pre = xn + r * hn;
            float n = 1.0f - 2.0f / (__expf(2.0f * pre) + 1.0f); // tanh
            float hnew = (1.0f - z) * n + z * h_reg;
            h_reg = hnew;
            outb[(size_t)t * 256 + tid] = hnew;
            float nb = __shfl_xor(hnew, 1);
            if (!(tid & 1)) {
                int k = tid >> 1;
                h2_t p; p[0] = (_Float16)hnew; p[1] = (_Float16)nb;
                *(unsigned int*)&hl2[k >> 5][(k & 31) * 2] = __builtin_bit_cast(unsigned int, p);
            }
        }
        __syncthreads();
    }

    if (tid < 256) out_hT[b * 256 + tid] = h_reg;
}

// ---------------------------------------------------------------- launch
extern "C" void kernel_launch(void* const* d_in, const int* in_sizes, int n_in,
                              void* d_out, int out_size, void* d_ws, size_t ws_size,
                              hipStream_t stream) {
    const float* x    = (const float*)d_in[0];
    const float* h0   = (const float*)d_in[1];
    const float* W_ih = (const float*)d_in[2];
    const float* W_hh = (const float*)d_in[3];
    const float* b_ih = (const float*)d_in[4];
    const float* b_hh = (const float*)d_in[5];
    float* out = (float*)d_out;

    char* ws = (char*)d_ws;
    float*          xg  = (float*)(ws);                      // 402,653,184 B
    unsigned short* xb  = (unsigned short*)(ws + 402653184); //  67,108,864 B
    unsigned short* wib = (unsigned short*)(ws + 469762048); //     393,216 B
    unsigned short* whp = (unsigned short*)(ws + 470155264); //     393,216 B
    float*          cb  = (float*)(ws + 470548480);          //       3,072 B

    cvt_bf16<<<4096, 256, 0, stream>>>(x, xb, 64 * 2048 * 256 / 4);
    cvt_bf16<<<192, 256, 0, stream>>>(W_ih, wib, 768 * 256 / 4);
    pack_whh<<<768, 256, 0, stream>>>(W_hh, whp);
    bias_comb<<<3, 256, 0, stream>>>(b_ih, b_hh, cb);
    proj_gemm<<<6144, 256, 0, stream>>>(xb, wib, cb, xg);
    gru_scan<<<64, 768, 0, stream>>>(xg, whp, b_hh, h0, out,
                                     out + (size_t)64 * 2048 * 256);
}